// Round 9
// baseline (800.686 us; speedup 1.0000x reference)
//
#include <hip/hip_runtime.h>
#include <math.h>

#define NN 256
#define NPIX 65536
#define NFIELD 81
#define NF2 41
#define FPAD 48              // psit row stride (floats), 12 float4s
#define NPAIR_PAD 1024
#define KCH3 32              // k per staged chunk
#define PTSTRIDE 91          // ptl row stride in float2 (bank-stride 22 -> 2-way, free)
#define EPSF 1e-8f

// ---------------- FFT helpers (256-point, LDS-resident) ----------------
// DIF: natural order in -> bit-reversed out.  DIT: bit-reversed in -> natural out.
// Composition DIF(inverse) -> pointwise -> DIT(forward) needs no explicit reversal.

__device__ inline void make_tw(float* twc, float* tws, int tid, int nthr) {
    for (int i = tid; i < 128; i += nthr) {
        float ang = (float)i * (6.283185307179586f / 256.0f);
        twc[i] = cosf(ang);
        tws[i] = sinf(ang);
    }
}

template<int T>
__device__ inline void dif_fft(float2* row, const float* twc, const float* tws,
                               float sgn, int lane) {
    #pragma unroll
    for (int s = 0; s < 8; ++s) {
        int half = 128 >> s;
        __syncthreads();
        #pragma unroll
        for (int bi = 0; bi < 128 / T; ++bi) {
            int b = lane + bi * T;
            int t = b & (half - 1);
            int blk = b >> (7 - s);
            int p0 = (blk << (8 - s)) + t;
            float2 u = row[p0];
            float2 v = row[p0 + half];
            row[p0] = make_float2(u.x + v.x, u.y + v.y);
            float dx = u.x - v.x, dy = u.y - v.y;
            int w = t << s;
            float c = twc[w], si = sgn * tws[w];
            row[p0 + half] = make_float2(dx * c - dy * si, dx * si + dy * c);
        }
    }
    __syncthreads();
}

template<int T>
__device__ inline void dit_fft(float2* row, const float* twc, const float* tws,
                               float sgn, int lane) {
    #pragma unroll
    for (int s = 0; s < 8; ++s) {
        int half = 1 << s;
        __syncthreads();
        #pragma unroll
        for (int bi = 0; bi < 128 / T; ++bi) {
            int b = lane + bi * T;
            int t = b & (half - 1);
            int blk = b >> s;
            int p0 = (blk << (s + 1)) + t;
            int w = t << (7 - s);
            float c = twc[w], si = sgn * tws[w];
            float2 v = row[p0 + half];
            float vx = v.x * c - v.y * si;
            float vy = v.x * si + v.y * c;
            float2 u = row[p0];
            row[p0] = make_float2(u.x + vx, u.y + vy);
            row[p0 + half] = make_float2(u.x - vx, u.y - vy);
        }
    }
    __syncthreads();
}

// ---------------- K0: psit[pix][f] = r^2 + i^2 (transposed, zero-padded) ----------------
__global__ void k0_psit(const float* __restrict__ r, const float* __restrict__ im,
                        float* __restrict__ psit) {
    __shared__ float tile[64 * FPAD];
    int tid = threadIdx.x;
    int base = blockIdx.x * 64;   // pixel base
    for (int idx = tid; idx < NF2 * 64; idx += 256) {
        int f = idx >> 6, px = idx & 63;
        size_t g = (size_t)f * NPIX + base + px;
        float a = r[g], b = im[g];
        tile[px * FPAD + f] = a * a + b * b;
    }
    for (int idx = tid; idx < 64 * (FPAD - NF2); idx += 256) {
        int px = idx / (FPAD - NF2), f = NF2 + idx % (FPAD - NF2);
        tile[px * FPAD + f] = 0.f;
    }
    __syncthreads();
    for (int idx = tid; idx < 64 * FPAD; idx += 256)
        psit[(size_t)base * FPAD + idx] = tile[idx];
}

// ---------------- K1: rows -> product with psi, inverse DIF over x ----------------
__global__ void k1_rowifft(const float* __restrict__ xhat,
                           const float* __restrict__ psiR,
                           const float* __restrict__ psiI,
                           float2* __restrict__ P) {
    __shared__ float2 buf[4][257];
    __shared__ float twc[128], tws[128];
    int tid = threadIdx.x;
    make_tw(twc, tws, tid, 256);
    int fi = tid >> 6, lane = tid & 63;
    int f = blockIdx.y;
    int y = blockIdx.x * 4 + fi;
    const float inv = 1.0f / 256.0f;
    size_t rb = (size_t)f * NPIX + (size_t)y * NN;
    for (int j = lane; j < NN; j += 64) {
        float xr = xhat[(y * NN + j) * 2 + 0];
        float xi = xhat[(y * NN + j) * 2 + 1];
        float pr = psiR[rb + j], pi = psiI[rb + j];
        buf[fi][j] = make_float2((xr * pr - xi * pi) * inv, (xr * pi + xi * pr) * inv);
    }
    dif_fft<64>(&buf[fi][0], twc, tws, +1.0f, lane);
    for (int j = lane; j < NN; j += 64) P[rb + j] = buf[fi][j];
}

// ---------------- K2: per column: inverse DIF over y, modulus, forward DIT over y ----------------
__global__ void k2_colpass(float2* __restrict__ P) {
    __shared__ float2 buf[16][257];
    __shared__ float twc[128], tws[128];
    int tid = threadIdx.x;      // 256 threads: 16 columns x 16 threads
    make_tw(twc, tws, tid, 256);
    int c = tid & 15, tl = tid >> 4;
    int f = blockIdx.y;
    int xb = blockIdx.x * 16;
    size_t fb = (size_t)f * NPIX;
    #pragma unroll
    for (int i = 0; i < 16; ++i) {
        int y = tl + i * 16;
        buf[c][y] = P[fb + (size_t)y * NN + xb + c];
    }
    dif_fft<16>(&buf[c][0], twc, tws, +1.0f, tl);
    const float inv = 1.0f / 256.0f;
    #pragma unroll
    for (int i = 0; i < 16; ++i) {
        int p = tl + i * 16;
        float2 v = buf[c][p];
        float vx = v.x * inv, vy = v.y * inv;
        buf[c][p] = make_float2(sqrtf(vx * vx + vy * vy + EPSF), 0.0f);
    }
    dit_fft<16>(&buf[c][0], twc, tws, -1.0f, tl);
    #pragma unroll
    for (int i = 0; i < 16; ++i) {
        int y = tl + i * 16;
        P[fb + (size_t)y * NN + xb + c] = buf[c][y];
    }
}

// ---------------- K3: rows -> forward DIT over x (consumes bitrev-x) ----------------
__global__ void k3_rowfft(float2* __restrict__ P) {
    __shared__ float2 buf[4][257];
    __shared__ float twc[128], tws[128];
    int tid = threadIdx.x;
    make_tw(twc, tws, tid, 256);
    int fi = tid >> 6, lane = tid & 63;
    int f = blockIdx.y;
    int y = blockIdx.x * 4 + fi;
    size_t rb = (size_t)f * NPIX + (size_t)y * NN;
    for (int j = lane; j < NN; j += 64) buf[fi][j] = P[rb + j];
    dit_fft<64>(&buf[fi][0], twc, tws, -1.0f, lane);
    for (int j = lane; j < NN; j += 64) P[rb + j] = buf[fi][j];
}

// ---------------- pair enumeration, SORTED by f-start group ----------------
// group g covers pairs [G[g], G[g+1]) with fstart = 8*g.
// Within group g: M pairs j=2g (36, tri a<=b), M pairs j=2g+1 (36),
//                 N pairs l=2g (8*l, skipped for g=0), N pairs l=2g+1 (8*l),
//                 then (g==4 only) A pairs (80).  s==800: s0.  801..1023: pad.
__device__ __host__ inline int fsj(int j) { int t = j >> 1; return (t > 4 ? 4 : t) * 8; }

__device__ inline int group_of(int s) {
    return (s < 80) ? 0 : (s < 192) ? 1 : (s < 336) ? 2 : (s < 512) ? 3 : 4;
}

__device__ inline void pair_sorted(int s, int& u, int& v) {
    if (s >= 800) { u = 80; v = 80; return; }   // s0 and pad
    const int Gs[5] = {0, 80, 192, 336, 512};
    int g = group_of(s);
    int r = s - Gs[g];
    if (r < 72) {                       // M section
        int j = 2 * g + (r >= 36);
        int rr = (r >= 36) ? r - 36 : r;
        int a = 0;
        while (rr >= 8 - a) { rr -= 8 - a; ++a; }
        int b = a + rr;
        u = a * 10 + j; v = b * 10 + j;
        return;
    }
    int r2 = r - 72;                    // N section
    int l0 = 2 * g;
    int c0 = (l0 >= 1) ? 8 * l0 : 0;
    if (r2 < c0) { int i = r2 / l0, j = r2 % l0; u = i * 10 + j; v = i * 10 + l0; return; }
    r2 -= c0;
    int l1 = 2 * g + 1;
    if (r2 < 8 * l1) { int i = r2 / l1, j = r2 % l1; u = i * 10 + j; v = i * 10 + l1; return; }
    r2 -= 8 * l1;                       // A section (g==4 only): r2 = i*10+j
    u = r2; v = 80;
}

// inverse maps (for c2): sorted index of each pair type
__device__ inline int pM(int a, int b, int j) {
    const int Gt[5] = {0, 80, 192, 336, 512};
    return Gt[j >> 1] + (j & 1) * 36 + a * 8 - a * (a - 1) / 2 + (b - a);
}
__device__ inline int pN(int i, int j, int l) {
    const int Gt[5] = {0, 80, 192, 336, 512};
    return Gt[l >> 1] + 72 + ((l & 1) ? 8 * (l - 1) : 0) + i * l + j;
}
// A pairs: 720 + i*10 + j ; s0: 800  (same as sorted layout)

// ---------------- C1: lane-per-pair, f-quad slab per template, acc <= 32 VGPR ----------------
template<int QLO, int NQ>
__device__ inline void c1_inner(const float2* __restrict__ ptl,
                                const float* __restrict__ psl,
                                int u, int v,
                                float (&ar)[NQ][4], float (&ai)[NQ][4]) {
    #pragma unroll 4
    for (int kk = 0; kk < KCH3; ++kk) {
        float2 A = ptl[kk * PTSTRIDE + u];
        float2 B = ptl[kk * PTSTRIDE + v];
        float cre = A.x * B.x + A.y * B.y;
        float cim = A.y * B.x - A.x * B.y;
        const float4* qr = (const float4*)&psl[kk * 16];
        #pragma unroll
        for (int q = QLO; q < NQ; ++q) {
            float4 pq = qr[q];
            ar[q][0] += pq.x * cre; ai[q][0] += pq.x * cim;
            ar[q][1] += pq.y * cre; ai[q][1] += pq.y * cim;
            ar[q][2] += pq.z * cre; ai[q][2] += pq.z * cim;
            ar[q][3] += pq.w * cre; ai[q][3] += pq.w * cim;
        }
    }
}

// SLAB covers f-quads [SLAB*4, SLAB*4+NQ). kpb = k-pixels per block (multiple of 32).
template<int SLAB>
__global__ void __launch_bounds__(256) c1_contract(const float2* __restrict__ P,
                                                   const float* __restrict__ psit,
                                                   float* __restrict__ Mout,
                                                   int kpb) {
    constexpr int NQ = (SLAB == 2) ? 3 : 4;
    __shared__ float2 ptl[KCH3 * PTSTRIDE];   // 23.3 KB: [k][field]
    __shared__ float  psl[KCH3 * 16];         // 2 KB:    [k][slab-f]
    int tid = threadIdx.x;
    int split = blockIdx.x, ptile = blockIdx.y;
    int p = ptile * 256 + tid;                // this lane's pair
    int u, v;
    pair_sorted(p, u, v);
    int wbase = ptile * 256 + (tid & ~63);
    int qs = 2 * group_of(wbase);             // wave's first needed f-quad
    int qlo = qs - SLAB * 4; if (qlo < 0) qlo = 0;
    if (wbase > 800) qlo = NQ;                // pure-pad wave: skip compute+flush
    qlo = __builtin_amdgcn_readfirstlane(qlo);
    float ar[NQ][4], ai[NQ][4];
    #pragma unroll
    for (int q = 0; q < NQ; ++q)
        #pragma unroll
        for (int fi = 0; fi < 4; ++fi) { ar[q][fi] = 0.f; ai[q][fi] = 0.f; }

    int nch = kpb >> 5;
    for (int ch = 0; ch < nch; ++ch) {
        int kbase = split * kpb + ch * KCH3;
        __syncthreads();
        // stage P fields: [kk][f], padded row stride 91 (2-way banks on write)
        for (int idx = tid; idx < NFIELD * KCH3; idx += 256) {
            int f = idx >> 5, kk = idx & 31;
            ptl[kk * PTSTRIDE + f] = P[(size_t)f * NPIX + kbase + kk];
        }
        // stage psi slab: [kk][16 floats]; 512 entries
        {
            int idx = tid;
            #pragma unroll
            for (int t = 0; t < 2; ++t, idx += 256) {
                int kk = idx >> 4, c = idx & 15;
                psl[idx] = psit[(size_t)(kbase + kk) * FPAD + SLAB * 16 + c];
            }
        }
        __syncthreads();
        if (qlo == 0)      c1_inner<0, NQ>(ptl, psl, u, v, ar, ai);
        else if (qlo == 2 && NQ > 2) c1_inner<(2 < NQ ? 2 : 0), NQ>(ptl, psl, u, v, ar, ai);
        // qlo >= NQ: wave idles through compute (still participates in staging)
    }
    if (qlo < NQ) {
        for (int q = qlo; q < NQ; ++q) {
            #pragma unroll
            for (int fi = 0; fi < 4; ++fi) {
                int f = (SLAB * 4 + q) * 4 + fi;
                atomicAdd(&Mout[((size_t)f * NPAIR_PAD + p) * 2 + 0], ar[q][fi]);
                atomicAdd(&Mout[((size_t)f * NPAIR_PAD + p) * 2 + 1], ai[q][fi]);
            }
        }
    }
}

// ---------------- C2: magnitude + assembly in reference output order ----------------
__device__ inline int seglen_d(int j, int i) {
    int s = (NF2 - fsj(j)) * (8 - i) + 9;
    for (int l = j + 1; l < 10; ++l) s += NF2 - fsj(l);
    return s;
}

__device__ inline float magof(const float* Mout, int f, int p) {
    const float nrm = 1.0f / 65536.0f;
    float re = Mout[((size_t)f * NPAIR_PAD + p) * 2 + 0] * nrm;
    float im = Mout[((size_t)f * NPAIR_PAD + p) * 2 + 1] * nrm;
    return sqrtf(re * re + im * im + EPSF);
}

__global__ void c2_assemble(const float* __restrict__ Mout, float* __restrict__ out) {
    int bid = blockIdx.x, tid = threadIdx.x;
    if (bid == 0) {
        if (tid == 0) out[0] = magof(Mout, 40, 800);   // s0
        return;
    }
    int idx = bid - 1;
    int j = idx / 8, i = idx % 8;
    int base = 1;
    for (int q = 0; q < idx; ++q) base += seglen_d(q / 8, q % 8);
    int fs = fsj(j);
    int d = 8 - i;
    int len1 = (NF2 - fs) * d;
    int total = seglen_d(j, i);
    for (int e = tid; e < total; e += 256) {
        int f, p;
        if (e < len1) {
            f = fs + e / d;
            int b = i + e % d;
            p = pM(i, b, j);
        } else {
            int e2 = e - len1;
            bool found = false;
            f = 0; p = 0;
            for (int l = j + 1; l < 10; ++l) {
                int ll = NF2 - fsj(l);
                if (e2 < ll) {
                    f = fsj(l) + e2;
                    p = pN(i, j, l);
                    found = true;
                    break;
                }
                e2 -= ll;
            }
            if (!found) { f = 32 + e2; p = 720 + i * 10 + j; }
        }
        out[base + e] = magof(Mout, f, p);
    }
}

// ---------------- launch ----------------
extern "C" void kernel_launch(void* const* d_in, const int* in_sizes, int n_in,
                              void* d_out, int out_size, void* d_ws, size_t ws_size,
                              hipStream_t stream) {
    const float* xhat  = (const float*)d_in[0];
    const float* psiR  = (const float*)d_in[1];
    const float* psiI  = (const float*)d_in[2];
    const float* p2R   = (const float*)d_in[3];
    const float* p2I   = (const float*)d_in[4];

    char* ws = (char*)d_ws;
    float2* P = (float2*)ws;
    size_t off = (size_t)NFIELD * NPIX * sizeof(float2);   // 42.47 MB
    float* psit = (float*)(ws + off);
    off += (size_t)NPIX * FPAD * sizeof(float);            // 12.58 MB
    float* Mout = (float*)(ws + off);
    size_t mout_bytes = (size_t)FPAD * NPAIR_PAD * 2 * sizeof(float);

    hipMemsetAsync(Mout, 0, mout_bytes, stream);

    k0_psit<<<dim3(NPIX / 64), dim3(256), 0, stream>>>(p2R, p2I, psit);
    k1_rowifft<<<dim3(64, NFIELD), dim3(256), 0, stream>>>(xhat, psiR, psiI, P);
    k2_colpass<<<dim3(16, NFIELD), dim3(256), 0, stream>>>(P);
    k3_rowfft<<<dim3(64, NFIELD), dim3(256), 0, stream>>>(P);
    // slab 0 (quads 0-3): pairs 0-255 only; k/block=64 -> 1024 blocks
    c1_contract<0><<<dim3(NPIX / 64, 1), dim3(256), 0, stream>>>(P, psit, Mout, 64);
    // slab 1 (quads 4-7): pairs 0-511; k/block=128 -> 1024 blocks
    c1_contract<1><<<dim3(NPIX / 128, 2), dim3(256), 0, stream>>>(P, psit, Mout, 128);
    // slab 2 (quads 8-10): all pairs; k/block=256 -> 1024 blocks
    c1_contract<2><<<dim3(NPIX / 256, 4), dim3(256), 0, stream>>>(P, psit, Mout, 256);
    c2_assemble<<<dim3(81), dim3(256), 0, stream>>>(Mout, (float*)d_out);
}

// Round 10
// 644.905 us; speedup vs baseline: 1.2416x; 1.2416x over previous
//
#include <hip/hip_runtime.h>
#include <math.h>

#define NN 256
#define NPIX 65536
#define NFIELD 81
#define NF2 41
#define FPAD 48              // psit row stride (floats), 12 float4s
#define NPAIR_PAD 1024
#define KC 16                // k per staged chunk
#define CSTR 257             // C row stride in float2 (write spread; reads lane-contiguous)
#define EPSF 1e-8f

// ---------------- FFT helpers (256-point, LDS-resident) ----------------
// DIF: natural order in -> bit-reversed out.  DIT: bit-reversed in -> natural out.
// Composition DIF(inverse) -> pointwise -> DIT(forward) needs no explicit reversal.

__device__ inline void make_tw(float* twc, float* tws, int tid, int nthr) {
    for (int i = tid; i < 128; i += nthr) {
        float ang = (float)i * (6.283185307179586f / 256.0f);
        twc[i] = cosf(ang);
        tws[i] = sinf(ang);
    }
}

template<int T>
__device__ inline void dif_fft(float2* row, const float* twc, const float* tws,
                               float sgn, int lane) {
    #pragma unroll
    for (int s = 0; s < 8; ++s) {
        int half = 128 >> s;
        __syncthreads();
        #pragma unroll
        for (int bi = 0; bi < 128 / T; ++bi) {
            int b = lane + bi * T;
            int t = b & (half - 1);
            int blk = b >> (7 - s);
            int p0 = (blk << (8 - s)) + t;
            float2 u = row[p0];
            float2 v = row[p0 + half];
            row[p0] = make_float2(u.x + v.x, u.y + v.y);
            float dx = u.x - v.x, dy = u.y - v.y;
            int w = t << s;
            float c = twc[w], si = sgn * tws[w];
            row[p0 + half] = make_float2(dx * c - dy * si, dx * si + dy * c);
        }
    }
    __syncthreads();
}

template<int T>
__device__ inline void dit_fft(float2* row, const float* twc, const float* tws,
                               float sgn, int lane) {
    #pragma unroll
    for (int s = 0; s < 8; ++s) {
        int half = 1 << s;
        __syncthreads();
        #pragma unroll
        for (int bi = 0; bi < 128 / T; ++bi) {
            int b = lane + bi * T;
            int t = b & (half - 1);
            int blk = b >> s;
            int p0 = (blk << (s + 1)) + t;
            int w = t << (7 - s);
            float c = twc[w], si = sgn * tws[w];
            float2 v = row[p0 + half];
            float vx = v.x * c - v.y * si;
            float vy = v.x * si + v.y * c;
            float2 u = row[p0];
            row[p0] = make_float2(u.x + vx, u.y + vy);
            row[p0 + half] = make_float2(u.x - vx, u.y - vy);
        }
    }
    __syncthreads();
}

// ---------------- K0: psit[pix][f] = r^2 + i^2 (transposed, zero-padded) ----------------
__global__ void k0_psit(const float* __restrict__ r, const float* __restrict__ im,
                        float* __restrict__ psit) {
    __shared__ float tile[64 * FPAD];
    int tid = threadIdx.x;
    int base = blockIdx.x * 64;   // pixel base
    for (int idx = tid; idx < NF2 * 64; idx += 256) {
        int f = idx >> 6, px = idx & 63;
        size_t g = (size_t)f * NPIX + base + px;
        float a = r[g], b = im[g];
        tile[px * FPAD + f] = a * a + b * b;
    }
    for (int idx = tid; idx < 64 * (FPAD - NF2); idx += 256) {
        int px = idx / (FPAD - NF2), f = NF2 + idx % (FPAD - NF2);
        tile[px * FPAD + f] = 0.f;
    }
    __syncthreads();
    for (int idx = tid; idx < 64 * FPAD; idx += 256)
        psit[(size_t)base * FPAD + idx] = tile[idx];
}

// ---------------- K1: rows -> product with psi, inverse DIF over x ----------------
__global__ void k1_rowifft(const float* __restrict__ xhat,
                           const float* __restrict__ psiR,
                           const float* __restrict__ psiI,
                           float2* __restrict__ P) {
    __shared__ float2 buf[4][257];
    __shared__ float twc[128], tws[128];
    int tid = threadIdx.x;
    make_tw(twc, tws, tid, 256);
    int fi = tid >> 6, lane = tid & 63;
    int f = blockIdx.y;
    int y = blockIdx.x * 4 + fi;
    const float inv = 1.0f / 256.0f;
    size_t rb = (size_t)f * NPIX + (size_t)y * NN;
    for (int j = lane; j < NN; j += 64) {
        float xr = xhat[(y * NN + j) * 2 + 0];
        float xi = xhat[(y * NN + j) * 2 + 1];
        float pr = psiR[rb + j], pi = psiI[rb + j];
        buf[fi][j] = make_float2((xr * pr - xi * pi) * inv, (xr * pi + xi * pr) * inv);
    }
    dif_fft<64>(&buf[fi][0], twc, tws, +1.0f, lane);
    for (int j = lane; j < NN; j += 64) P[rb + j] = buf[fi][j];
}

// ---------------- K2: per column: inverse DIF over y, modulus, forward DIT over y ----------------
__global__ void k2_colpass(float2* __restrict__ P) {
    __shared__ float2 buf[16][257];
    __shared__ float twc[128], tws[128];
    int tid = threadIdx.x;      // 256 threads: 16 columns x 16 threads
    make_tw(twc, tws, tid, 256);
    int c = tid & 15, tl = tid >> 4;
    int f = blockIdx.y;
    int xb = blockIdx.x * 16;
    size_t fb = (size_t)f * NPIX;
    #pragma unroll
    for (int i = 0; i < 16; ++i) {
        int y = tl + i * 16;
        buf[c][y] = P[fb + (size_t)y * NN + xb + c];
    }
    dif_fft<16>(&buf[c][0], twc, tws, +1.0f, tl);
    const float inv = 1.0f / 256.0f;
    #pragma unroll
    for (int i = 0; i < 16; ++i) {
        int p = tl + i * 16;
        float2 v = buf[c][p];
        float vx = v.x * inv, vy = v.y * inv;
        buf[c][p] = make_float2(sqrtf(vx * vx + vy * vy + EPSF), 0.0f);
    }
    dit_fft<16>(&buf[c][0], twc, tws, -1.0f, tl);
    #pragma unroll
    for (int i = 0; i < 16; ++i) {
        int y = tl + i * 16;
        P[fb + (size_t)y * NN + xb + c] = buf[c][y];
    }
}

// ---------------- K3: rows -> forward DIT over x (consumes bitrev-x) ----------------
__global__ void k3_rowfft(float2* __restrict__ P) {
    __shared__ float2 buf[4][257];
    __shared__ float twc[128], tws[128];
    int tid = threadIdx.x;
    make_tw(twc, tws, tid, 256);
    int fi = tid >> 6, lane = tid & 63;
    int f = blockIdx.y;
    int y = blockIdx.x * 4 + fi;
    size_t rb = (size_t)f * NPIX + (size_t)y * NN;
    for (int j = lane; j < NN; j += 64) buf[fi][j] = P[rb + j];
    dit_fft<64>(&buf[fi][0], twc, tws, -1.0f, lane);
    for (int j = lane; j < NN; j += 64) P[rb + j] = buf[fi][j];
}

// ---------------- pair enumeration, SORTED by f-start group ----------------
// group g covers pairs [G[g], G[g+1]) with fstart = 8*g.
// Within group g: M pairs j=2g (36, tri a<=b), M pairs j=2g+1 (36),
//                 N pairs l=2g (8*l, skipped for g=0), N pairs l=2g+1 (8*l),
//                 then (g==4 only) A pairs (80).  s==800: s0.  801..1023: pad.
__device__ __host__ inline int fsj(int j) { int t = j >> 1; return (t > 4 ? 4 : t) * 8; }

__device__ inline int group_of(int s) {
    return (s < 80) ? 0 : (s < 192) ? 1 : (s < 336) ? 2 : (s < 512) ? 3 : 4;
}

__device__ inline void pair_sorted(int s, int& u, int& v) {
    if (s >= 800) { u = 80; v = 80; return; }   // s0 and pad
    const int Gs[5] = {0, 80, 192, 336, 512};
    int g = group_of(s);
    int r = s - Gs[g];
    if (r < 72) {                       // M section
        int j = 2 * g + (r >= 36);
        int rr = (r >= 36) ? r - 36 : r;
        int a = 0;
        while (rr >= 8 - a) { rr -= 8 - a; ++a; }
        int b = a + rr;
        u = a * 10 + j; v = b * 10 + j;
        return;
    }
    int r2 = r - 72;                    // N section
    int l0 = 2 * g;
    int c0 = (l0 >= 1) ? 8 * l0 : 0;
    if (r2 < c0) { int i = r2 / l0, j = r2 % l0; u = i * 10 + j; v = i * 10 + l0; return; }
    r2 -= c0;
    int l1 = 2 * g + 1;
    if (r2 < 8 * l1) { int i = r2 / l1, j = r2 % l1; u = i * 10 + j; v = i * 10 + l1; return; }
    r2 -= 8 * l1;                       // A section (g==4 only): r2 = i*10+j
    u = r2; v = 80;
}

// inverse maps (for c2): sorted index of each pair type
__device__ inline int pM(int a, int b, int j) {
    const int Gt[5] = {0, 80, 192, 336, 512};
    return Gt[j >> 1] + (j & 1) * 36 + a * 8 - a * (a - 1) / 2 + (b - a);
}
__device__ inline int pN(int i, int j, int l) {
    const int Gt[5] = {0, 80, 192, 336, 512};
    return Gt[l >> 1] + 72 + ((l & 1) ? 8 * (l - 1) : 0) + i * l + j;
}
// A pairs: 720 + i*10 + j ; s0: 800  (same as sorted layout)

// ---------------- C1: f-slab Z (quads 4Z..4Z+3), 256 pairs/block ----------------
// 4 waves: wave w -> quad-pair qp=w>>1 (2 quads), pair-half=w&1 (128 pairs).
// Thread: 2 quads x 4 f x 2 pairs = 32 acc, ALL statically indexed (rule #20).
// Per k: 2 broadcast b128 psi reads (free) + 2 lane-contiguous b64 C reads + 32 FMA.
template<int Z, int SPL>
__global__ void __launch_bounds__(256) c1z(const float2* __restrict__ P,
                                           const float* __restrict__ psit,
                                           float* __restrict__ Mout) {
    constexpr int NCHK = NPIX / SPL / KC;
    __shared__ float2 Cl[KC * CSTR];    // 32.9 KB: [k][pair]
    __shared__ float  psl[KC * 16];     // 1 KB:    [k][slab-f]
    __shared__ int    su[256], sv[256]; // 2 KB
    int tid = threadIdx.x;
    int split = blockIdx.x, tile = blockIdx.y;
    int pbase = tile * 256;
    {
        int u, v;
        pair_sorted(pbase + tid, u, v);
        su[tid] = u; sv[tid] = v;
    }
    int lane = tid & 63;
    int wv = tid >> 6;
    int qp = wv >> 1;            // 0..1: which quad pair of the slab
    int half = wv & 1;           // 0..1: which 128-pair half
    int p0 = half * 128 + lane;  // block-local pair
    int kl = tid & 15, prow = tid >> 4;
    float ar[2][4][2], ai[2][4][2];
    #pragma unroll
    for (int a = 0; a < 2; ++a)
        #pragma unroll
        for (int b = 0; b < 4; ++b)
            #pragma unroll
            for (int c = 0; c < 2; ++c) { ar[a][b][c] = 0.f; ai[a][b][c] = 0.f; }

    for (int ch = 0; ch < NCHK; ++ch) {
        int kb = split * (NPIX / SPL) + ch * KC;
        __syncthreads();   // protects LUT (first iter) and Cl reuse
        // psi slab: [k][16 f], one float per thread
        psl[tid] = psit[(size_t)(kb + (tid >> 4)) * FPAD + Z * 16 + (tid & 15)];
        // C tile: lanes 0-15 contiguous in k (coalesced), 16 pairs per thread
        #pragma unroll 4
        for (int i = 0; i < 16; ++i) {
            int pair = prow + 16 * i;
            int u = su[pair], v = sv[pair];
            float2 A = P[(size_t)u * NPIX + kb + kl];
            float2 B = P[(size_t)v * NPIX + kb + kl];
            Cl[kl * CSTR + pair] = make_float2(A.x * B.x + A.y * B.y,
                                               A.y * B.x - A.x * B.y);
        }
        __syncthreads();
        #pragma unroll 4
        for (int k = 0; k < KC; ++k) {
            float4 pA = *(const float4*)&psl[k * 16 + qp * 8];      // quad 2qp (broadcast)
            float4 pB = *(const float4*)&psl[k * 16 + qp * 8 + 4];  // quad 2qp+1
            float2 cc0 = Cl[k * CSTR + p0];
            float2 cc1 = Cl[k * CSTR + p0 + 64];
            float pq[2][4] = {{pA.x, pA.y, pA.z, pA.w}, {pB.x, pB.y, pB.z, pB.w}};
            float cr[2] = {cc0.x, cc1.x};
            float ci[2] = {cc0.y, cc1.y};
            #pragma unroll
            for (int qq = 0; qq < 2; ++qq)
                #pragma unroll
                for (int fi = 0; fi < 4; ++fi)
                    #pragma unroll
                    for (int m = 0; m < 2; ++m) {
                        ar[qq][fi][m] += pq[qq][fi] * cr[m];
                        ai[qq][fi][m] += pq[qq][fi] * ci[m];
                    }
        }
    }
    #pragma unroll
    for (int qq = 0; qq < 2; ++qq)
        #pragma unroll
        for (int fi = 0; fi < 4; ++fi)
            #pragma unroll
            for (int m = 0; m < 2; ++m) {
                int f = Z * 16 + (qp * 2 + qq) * 4 + fi;   // runtime addr math, static reg idx
                int p = pbase + p0 + m * 64;
                atomicAdd(&Mout[((size_t)f * NPAIR_PAD + p) * 2 + 0], ar[qq][fi][m]);
                atomicAdd(&Mout[((size_t)f * NPAIR_PAD + p) * 2 + 1], ai[qq][fi][m]);
            }
}

// ---------------- C2: magnitude + assembly in reference output order ----------------
__device__ inline int seglen_d(int j, int i) {
    int s = (NF2 - fsj(j)) * (8 - i) + 9;
    for (int l = j + 1; l < 10; ++l) s += NF2 - fsj(l);
    return s;
}

__device__ inline float magof(const float* Mout, int f, int p) {
    const float nrm = 1.0f / 65536.0f;
    float re = Mout[((size_t)f * NPAIR_PAD + p) * 2 + 0] * nrm;
    float im = Mout[((size_t)f * NPAIR_PAD + p) * 2 + 1] * nrm;
    return sqrtf(re * re + im * im + EPSF);
}

__global__ void c2_assemble(const float* __restrict__ Mout, float* __restrict__ out) {
    int bid = blockIdx.x, tid = threadIdx.x;
    if (bid == 0) {
        if (tid == 0) out[0] = magof(Mout, 40, 800);   // s0
        return;
    }
    int idx = bid - 1;
    int j = idx / 8, i = idx % 8;
    int base = 1;
    for (int q = 0; q < idx; ++q) base += seglen_d(q / 8, q % 8);
    int fs = fsj(j);
    int d = 8 - i;
    int len1 = (NF2 - fs) * d;
    int total = seglen_d(j, i);
    for (int e = tid; e < total; e += 256) {
        int f, p;
        if (e < len1) {
            f = fs + e / d;
            int b = i + e % d;
            p = pM(i, b, j);
        } else {
            int e2 = e - len1;
            bool found = false;
            f = 0; p = 0;
            for (int l = j + 1; l < 10; ++l) {
                int ll = NF2 - fsj(l);
                if (e2 < ll) {
                    f = fsj(l) + e2;
                    p = pN(i, j, l);
                    found = true;
                    break;
                }
                e2 -= ll;
            }
            if (!found) { f = 32 + e2; p = 720 + i * 10 + j; }
        }
        out[base + e] = magof(Mout, f, p);
    }
}

// ---------------- launch ----------------
extern "C" void kernel_launch(void* const* d_in, const int* in_sizes, int n_in,
                              void* d_out, int out_size, void* d_ws, size_t ws_size,
                              hipStream_t stream) {
    const float* xhat  = (const float*)d_in[0];
    const float* psiR  = (const float*)d_in[1];
    const float* psiI  = (const float*)d_in[2];
    const float* p2R   = (const float*)d_in[3];
    const float* p2I   = (const float*)d_in[4];

    char* ws = (char*)d_ws;
    float2* P = (float2*)ws;
    size_t off = (size_t)NFIELD * NPIX * sizeof(float2);   // 42.47 MB
    float* psit = (float*)(ws + off);
    off += (size_t)NPIX * FPAD * sizeof(float);            // 12.58 MB
    float* Mout = (float*)(ws + off);
    size_t mout_bytes = (size_t)FPAD * NPAIR_PAD * 2 * sizeof(float);

    hipMemsetAsync(Mout, 0, mout_bytes, stream);

    k0_psit<<<dim3(NPIX / 64), dim3(256), 0, stream>>>(p2R, p2I, psit);
    k1_rowifft<<<dim3(64, NFIELD), dim3(256), 0, stream>>>(xhat, psiR, psiI, P);
    k2_colpass<<<dim3(16, NFIELD), dim3(256), 0, stream>>>(P);
    k3_rowfft<<<dim3(64, NFIELD), dim3(256), 0, stream>>>(P);
    // Z=0: f0-15, needed only by pairs 0-191 -> tile0 (pairs 0-255); 512 k-splits
    c1z<0, 512><<<dim3(512, 1), dim3(256), 0, stream>>>(P, psit, Mout);
    // Z=1: f16-31, needed by pairs 0-511 -> tiles 0,1; 256 k-splits
    c1z<1, 256><<<dim3(256, 2), dim3(256), 0, stream>>>(P, psit, Mout);
    // Z=2: f32-47 (41+ zero-psi), all pairs -> tiles 0..3; 128 k-splits
    c1z<2, 128><<<dim3(128, 4), dim3(256), 0, stream>>>(P, psit, Mout);
    c2_assemble<<<dim3(81), dim3(256), 0, stream>>>(Mout, (float*)d_out);
}

// Round 11
// 407.704 us; speedup vs baseline: 1.9639x; 1.5818x over previous
//
#include <hip/hip_runtime.h>
#include <math.h>

#define NN 256
#define NPIX 65536
#define NFIELD 81
#define NF2 41
#define FPAD 48              // psit row stride (floats), 12 float4s
#define NPAIR_PAD 1024
#define KC 16                // k per staged chunk
#define CSTR 257             // C row stride in float2 (write spread; reads lane-contiguous)
#define NSPL 128             // k-splits
#define KPB (NPIX / NSPL)    // 512 k per block
#define NCHK (KPB / KC)      // 32 chunks
#define EPSF 1e-8f

// ---------------- FFT helpers (256-point, LDS-resident) ----------------
// DIF: natural order in -> bit-reversed out.  DIT: bit-reversed in -> natural out.
// Composition DIF(inverse) -> pointwise -> DIT(forward) needs no explicit reversal.

__device__ inline void make_tw(float* twc, float* tws, int tid, int nthr) {
    for (int i = tid; i < 128; i += nthr) {
        float ang = (float)i * (6.283185307179586f / 256.0f);
        twc[i] = cosf(ang);
        tws[i] = sinf(ang);
    }
}

template<int T>
__device__ inline void dif_fft(float2* row, const float* twc, const float* tws,
                               float sgn, int lane) {
    #pragma unroll
    for (int s = 0; s < 8; ++s) {
        int half = 128 >> s;
        __syncthreads();
        #pragma unroll
        for (int bi = 0; bi < 128 / T; ++bi) {
            int b = lane + bi * T;
            int t = b & (half - 1);
            int blk = b >> (7 - s);
            int p0 = (blk << (8 - s)) + t;
            float2 u = row[p0];
            float2 v = row[p0 + half];
            row[p0] = make_float2(u.x + v.x, u.y + v.y);
            float dx = u.x - v.x, dy = u.y - v.y;
            int w = t << s;
            float c = twc[w], si = sgn * tws[w];
            row[p0 + half] = make_float2(dx * c - dy * si, dx * si + dy * c);
        }
    }
    __syncthreads();
}

template<int T>
__device__ inline void dit_fft(float2* row, const float* twc, const float* tws,
                               float sgn, int lane) {
    #pragma unroll
    for (int s = 0; s < 8; ++s) {
        int half = 1 << s;
        __syncthreads();
        #pragma unroll
        for (int bi = 0; bi < 128 / T; ++bi) {
            int b = lane + bi * T;
            int t = b & (half - 1);
            int blk = b >> s;
            int p0 = (blk << (s + 1)) + t;
            int w = t << (7 - s);
            float c = twc[w], si = sgn * tws[w];
            float2 v = row[p0 + half];
            float vx = v.x * c - v.y * si;
            float vy = v.x * si + v.y * c;
            float2 u = row[p0];
            row[p0] = make_float2(u.x + vx, u.y + vy);
            row[p0 + half] = make_float2(u.x - vx, u.y - vy);
        }
    }
    __syncthreads();
}

// ---------------- K0: psit[pix][f] = r^2 + i^2 (transposed, zero-padded) ----------------
__global__ void k0_psit(const float* __restrict__ r, const float* __restrict__ im,
                        float* __restrict__ psit) {
    __shared__ float tile[64 * FPAD];
    int tid = threadIdx.x;
    int base = blockIdx.x * 64;   // pixel base
    for (int idx = tid; idx < NF2 * 64; idx += 256) {
        int f = idx >> 6, px = idx & 63;
        size_t g = (size_t)f * NPIX + base + px;
        float a = r[g], b = im[g];
        tile[px * FPAD + f] = a * a + b * b;
    }
    for (int idx = tid; idx < 64 * (FPAD - NF2); idx += 256) {
        int px = idx / (FPAD - NF2), f = NF2 + idx % (FPAD - NF2);
        tile[px * FPAD + f] = 0.f;
    }
    __syncthreads();
    for (int idx = tid; idx < 64 * FPAD; idx += 256)
        psit[(size_t)base * FPAD + idx] = tile[idx];
}

// ---------------- K1: rows -> product with psi, inverse DIF over x ----------------
__global__ void k1_rowifft(const float* __restrict__ xhat,
                           const float* __restrict__ psiR,
                           const float* __restrict__ psiI,
                           float2* __restrict__ P) {
    __shared__ float2 buf[4][257];
    __shared__ float twc[128], tws[128];
    int tid = threadIdx.x;
    make_tw(twc, tws, tid, 256);
    int fi = tid >> 6, lane = tid & 63;
    int f = blockIdx.y;
    int y = blockIdx.x * 4 + fi;
    const float inv = 1.0f / 256.0f;
    size_t rb = (size_t)f * NPIX + (size_t)y * NN;
    for (int j = lane; j < NN; j += 64) {
        float xr = xhat[(y * NN + j) * 2 + 0];
        float xi = xhat[(y * NN + j) * 2 + 1];
        float pr = psiR[rb + j], pi = psiI[rb + j];
        buf[fi][j] = make_float2((xr * pr - xi * pi) * inv, (xr * pi + xi * pr) * inv);
    }
    dif_fft<64>(&buf[fi][0], twc, tws, +1.0f, lane);
    for (int j = lane; j < NN; j += 64) P[rb + j] = buf[fi][j];
}

// ---------------- K2: per column: inverse DIF over y, modulus, forward DIT over y ----------------
__global__ void k2_colpass(float2* __restrict__ P) {
    __shared__ float2 buf[16][257];
    __shared__ float twc[128], tws[128];
    int tid = threadIdx.x;      // 256 threads: 16 columns x 16 threads
    make_tw(twc, tws, tid, 256);
    int c = tid & 15, tl = tid >> 4;
    int f = blockIdx.y;
    int xb = blockIdx.x * 16;
    size_t fb = (size_t)f * NPIX;
    #pragma unroll
    for (int i = 0; i < 16; ++i) {
        int y = tl + i * 16;
        buf[c][y] = P[fb + (size_t)y * NN + xb + c];
    }
    dif_fft<16>(&buf[c][0], twc, tws, +1.0f, tl);
    const float inv = 1.0f / 256.0f;
    #pragma unroll
    for (int i = 0; i < 16; ++i) {
        int p = tl + i * 16;
        float2 v = buf[c][p];
        float vx = v.x * inv, vy = v.y * inv;
        buf[c][p] = make_float2(sqrtf(vx * vx + vy * vy + EPSF), 0.0f);
    }
    dit_fft<16>(&buf[c][0], twc, tws, -1.0f, tl);
    #pragma unroll
    for (int i = 0; i < 16; ++i) {
        int y = tl + i * 16;
        P[fb + (size_t)y * NN + xb + c] = buf[c][y];
    }
}

// ---------------- K3: rows -> forward DIT over x (consumes bitrev-x) ----------------
__global__ void k3_rowfft(float2* __restrict__ P) {
    __shared__ float2 buf[4][257];
    __shared__ float twc[128], tws[128];
    int tid = threadIdx.x;
    make_tw(twc, tws, tid, 256);
    int fi = tid >> 6, lane = tid & 63;
    int f = blockIdx.y;
    int y = blockIdx.x * 4 + fi;
    size_t rb = (size_t)f * NPIX + (size_t)y * NN;
    for (int j = lane; j < NN; j += 64) buf[fi][j] = P[rb + j];
    dit_fft<64>(&buf[fi][0], twc, tws, -1.0f, lane);
    for (int j = lane; j < NN; j += 64) P[rb + j] = buf[fi][j];
}

// ---------------- pair enumeration, SORTED by f-start group ----------------
// group g covers pairs [G[g], G[g+1]) with fstart = 8*g.
// Within group g: M pairs j=2g (36, tri a<=b), M pairs j=2g+1 (36),
//                 N pairs l=2g (8*l, skipped for g=0), N pairs l=2g+1 (8*l),
//                 then (g==4 only) A pairs (80).  s==800: s0.  801..1023: pad.
__device__ __host__ inline int fsj(int j) { int t = j >> 1; return (t > 4 ? 4 : t) * 8; }

__device__ inline int group_of(int s) {
    return (s < 80) ? 0 : (s < 192) ? 1 : (s < 336) ? 2 : (s < 512) ? 3 : 4;
}

__device__ inline void pair_sorted(int s, int& u, int& v) {
    if (s >= 800) { u = 80; v = 80; return; }   // s0 and pad
    const int Gs[5] = {0, 80, 192, 336, 512};
    int g = group_of(s);
    int r = s - Gs[g];
    if (r < 72) {                       // M section
        int j = 2 * g + (r >= 36);
        int rr = (r >= 36) ? r - 36 : r;
        int a = 0;
        while (rr >= 8 - a) { rr -= 8 - a; ++a; }
        int b = a + rr;
        u = a * 10 + j; v = b * 10 + j;
        return;
    }
    int r2 = r - 72;                    // N section
    int l0 = 2 * g;
    int c0 = (l0 >= 1) ? 8 * l0 : 0;
    if (r2 < c0) { int i = r2 / l0, j = r2 % l0; u = i * 10 + j; v = i * 10 + l0; return; }
    r2 -= c0;
    int l1 = 2 * g + 1;
    if (r2 < 8 * l1) { int i = r2 / l1, j = r2 % l1; u = i * 10 + j; v = i * 10 + l1; return; }
    r2 -= 8 * l1;                       // A section (g==4 only): r2 = i*10+j
    u = r2; v = 80;
}

// inverse maps (for c2): sorted index of each pair type
__device__ inline int pM(int a, int b, int j) {
    const int Gt[5] = {0, 80, 192, 336, 512};
    return Gt[j >> 1] + (j & 1) * 36 + a * 8 - a * (a - 1) / 2 + (b - a);
}
__device__ inline int pN(int i, int j, int l) {
    const int Gt[5] = {0, 80, 192, 336, 512};
    return Gt[l >> 1] + 72 + ((l & 1) ? 8 * (l - 1) : 0) + i * l + j;
}
// A pairs: 720 + i*10 + j ; s0: 800  (same as sorted layout)

// ---------------- C1: merged slabs, non-atomic split-K partials ----------------
// blockIdx.y -> (z, tile): {0:(0,0), 1:(1,0), 2:(1,1), 3:(2,0), 4:(2,1), 5:(2,2), 6:(2,3)}
// Block: 4 waves; wave w -> quad-pair qp=w>>1 (2 quads of slab z), pair-half=w&1.
// Thread: 2 quads x 4 f x 2 pairs = 32 acc, ALL statically indexed (rule #20).
// Output: plain coalesced float2 stores to private Mpart slot (NO atomics).
__global__ void __launch_bounds__(256) c1all(const float2* __restrict__ P,
                                             const float* __restrict__ psit,
                                             float* __restrict__ Mpart) {
    __shared__ float2 Cl[KC * CSTR];    // 32.9 KB: [k][pair]
    __shared__ float  psl[KC * 16];     // 1 KB:    [k][slab-f]
    __shared__ int    su[256], sv[256]; // 2 KB
    int tid = threadIdx.x;
    int split = blockIdx.x, y = blockIdx.y;
    int z    = (y == 0) ? 0 : (y <= 2) ? 1 : 2;
    int tile = (y == 0) ? 0 : (y <= 2) ? (y - 1) : (y - 3);
    int pbase = tile * 256;
    {
        int u, v;
        pair_sorted(pbase + tid, u, v);
        su[tid] = u; sv[tid] = v;
    }
    int lane = tid & 63;
    int wv = tid >> 6;
    int qp = wv >> 1;            // 0..1: which quad pair of the slab
    int half = wv & 1;           // 0..1: which 128-pair half
    int p0 = half * 128 + lane;  // block-local pair
    int kl = tid & 15, prow = tid >> 4;
    float ar[2][4][2], ai[2][4][2];
    #pragma unroll
    for (int a = 0; a < 2; ++a)
        #pragma unroll
        for (int b = 0; b < 4; ++b)
            #pragma unroll
            for (int c = 0; c < 2; ++c) { ar[a][b][c] = 0.f; ai[a][b][c] = 0.f; }

    for (int ch = 0; ch < NCHK; ++ch) {
        int kb = split * KPB + ch * KC;
        __syncthreads();   // protects LUT (first iter) and Cl reuse
        // psi slab: [k][16 f], one float per thread
        psl[tid] = psit[(size_t)(kb + (tid >> 4)) * FPAD + z * 16 + (tid & 15)];
        // C tile: lanes 0-15 contiguous in k (coalesced), 16 pairs per thread
        #pragma unroll 4
        for (int i = 0; i < 16; ++i) {
            int pair = prow + 16 * i;
            int u = su[pair], v = sv[pair];
            float2 A = P[(size_t)u * NPIX + kb + kl];
            float2 B = P[(size_t)v * NPIX + kb + kl];
            Cl[kl * CSTR + pair] = make_float2(A.x * B.x + A.y * B.y,
                                               A.y * B.x - A.x * B.y);
        }
        __syncthreads();
        #pragma unroll 4
        for (int k = 0; k < KC; ++k) {
            float4 pA = *(const float4*)&psl[k * 16 + qp * 8];      // quad 2qp (broadcast)
            float4 pB = *(const float4*)&psl[k * 16 + qp * 8 + 4];  // quad 2qp+1
            float2 cc0 = Cl[k * CSTR + p0];
            float2 cc1 = Cl[k * CSTR + p0 + 64];
            float pq[2][4] = {{pA.x, pA.y, pA.z, pA.w}, {pB.x, pB.y, pB.z, pB.w}};
            float cr[2] = {cc0.x, cc1.x};
            float ci[2] = {cc0.y, cc1.y};
            #pragma unroll
            for (int qq = 0; qq < 2; ++qq)
                #pragma unroll
                for (int fi = 0; fi < 4; ++fi)
                    #pragma unroll
                    for (int m = 0; m < 2; ++m) {
                        ar[qq][fi][m] += pq[qq][fi] * cr[m];
                        ai[qq][fi][m] += pq[qq][fi] * ci[m];
                    }
        }
    }
    // private partial slot: [y*NSPL+split][fl(16)][pl(256)] float2, plain stores
    float2* out = (float2*)Mpart + (size_t)(y * NSPL + split) * 4096;
    #pragma unroll
    for (int qq = 0; qq < 2; ++qq)
        #pragma unroll
        for (int fi = 0; fi < 4; ++fi)
            #pragma unroll
            for (int m = 0; m < 2; ++m) {
                int fl = (qp * 2 + qq) * 4 + fi;   // runtime addr math, static reg idx
                out[fl * 256 + p0 + m * 64] = make_float2(ar[qq][fi][m], ai[qq][fi][m]);
            }
}

// ---------------- C1R: reduce split partials into Mout ----------------
__global__ void __launch_bounds__(256) c1red(const float* __restrict__ Mpart,
                                             float* __restrict__ Mout) {
    int y = blockIdx.x, fl = blockIdx.y;
    int pl = threadIdx.x;
    int z    = (y == 0) ? 0 : (y <= 2) ? 1 : 2;
    int tile = (y == 0) ? 0 : (y <= 2) ? (y - 1) : (y - 3);
    const float2* mp = (const float2*)Mpart;
    size_t cell = (size_t)fl * 256 + pl;
    float sx = 0.f, sy = 0.f;
    #pragma unroll 8
    for (int sp = 0; sp < NSPL; ++sp) {
        float2 v = mp[(size_t)(y * NSPL + sp) * 4096 + cell];
        sx += v.x; sy += v.y;
    }
    int f = z * 16 + fl, p = tile * 256 + pl;
    ((float2*)Mout)[(size_t)f * NPAIR_PAD + p] = make_float2(sx, sy);
}

// ---------------- C2: magnitude + assembly in reference output order ----------------
__device__ inline int seglen_d(int j, int i) {
    int s = (NF2 - fsj(j)) * (8 - i) + 9;
    for (int l = j + 1; l < 10; ++l) s += NF2 - fsj(l);
    return s;
}

__device__ inline float magof(const float* Mout, int f, int p) {
    const float nrm = 1.0f / 65536.0f;
    float re = Mout[((size_t)f * NPAIR_PAD + p) * 2 + 0] * nrm;
    float im = Mout[((size_t)f * NPAIR_PAD + p) * 2 + 1] * nrm;
    return sqrtf(re * re + im * im + EPSF);
}

__global__ void c2_assemble(const float* __restrict__ Mout, float* __restrict__ out) {
    int bid = blockIdx.x, tid = threadIdx.x;
    if (bid == 0) {
        if (tid == 0) out[0] = magof(Mout, 40, 800);   // s0
        return;
    }
    int idx = bid - 1;
    int j = idx / 8, i = idx % 8;
    int base = 1;
    for (int q = 0; q < idx; ++q) base += seglen_d(q / 8, q % 8);
    int fs = fsj(j);
    int d = 8 - i;
    int len1 = (NF2 - fs) * d;
    int total = seglen_d(j, i);
    for (int e = tid; e < total; e += 256) {
        int f, p;
        if (e < len1) {
            f = fs + e / d;
            int b = i + e % d;
            p = pM(i, b, j);
        } else {
            int e2 = e - len1;
            bool found = false;
            f = 0; p = 0;
            for (int l = j + 1; l < 10; ++l) {
                int ll = NF2 - fsj(l);
                if (e2 < ll) {
                    f = fsj(l) + e2;
                    p = pN(i, j, l);
                    found = true;
                    break;
                }
                e2 -= ll;
            }
            if (!found) { f = 32 + e2; p = 720 + i * 10 + j; }
        }
        out[base + e] = magof(Mout, f, p);
    }
}

// ---------------- launch ----------------
extern "C" void kernel_launch(void* const* d_in, const int* in_sizes, int n_in,
                              void* d_out, int out_size, void* d_ws, size_t ws_size,
                              hipStream_t stream) {
    const float* xhat  = (const float*)d_in[0];
    const float* psiR  = (const float*)d_in[1];
    const float* psiI  = (const float*)d_in[2];
    const float* p2R   = (const float*)d_in[3];
    const float* p2I   = (const float*)d_in[4];

    char* ws = (char*)d_ws;
    float2* P = (float2*)ws;
    size_t off = (size_t)NFIELD * NPIX * sizeof(float2);   // 42.47 MB
    float* psit = (float*)(ws + off);
    off += (size_t)NPIX * FPAD * sizeof(float);            // 12.58 MB
    float* Mpart = (float*)(ws + off);
    off += (size_t)7 * NSPL * 4096 * 2 * sizeof(float);    // 29.36 MB
    float* Mout = (float*)(ws + off);                      // 0.39 MB

    k0_psit<<<dim3(NPIX / 64), dim3(256), 0, stream>>>(p2R, p2I, psit);
    k1_rowifft<<<dim3(64, NFIELD), dim3(256), 0, stream>>>(xhat, psiR, psiI, P);
    k2_colpass<<<dim3(16, NFIELD), dim3(256), 0, stream>>>(P);
    k3_rowfft<<<dim3(64, NFIELD), dim3(256), 0, stream>>>(P);
    c1all<<<dim3(NSPL, 7), dim3(256), 0, stream>>>(P, psit, Mpart);
    c1red<<<dim3(7, 16), dim3(256), 0, stream>>>(Mpart, Mout);
    c2_assemble<<<dim3(81), dim3(256), 0, stream>>>(Mout, (float*)d_out);
}

// Round 12
// 401.409 us; speedup vs baseline: 1.9947x; 1.0157x over previous
//
#include <hip/hip_runtime.h>
#include <math.h>

#define NN 256
#define NPIX 65536
#define NFIELD 81
#define NF2 41
#define FPAD 48              // psit row stride (floats), 12 float4s
#define NPAIR_PAD 1024
#define KC 8                 // k per staged chunk (double-buffered)
#define CSTR 257             // C row stride in float2
#define NSPL 128             // k-splits
#define KPB (NPIX / NSPL)    // 512 k per block
#define NCHK (KPB / KC)      // 64 chunks
#define EPSF 1e-8f

// ---------------- FFT helpers (256-point, LDS-resident) ----------------
// DIF: natural order in -> bit-reversed out.  DIT: bit-reversed in -> natural out.
// Composition DIF(inverse) -> pointwise -> DIT(forward) needs no explicit reversal.

__device__ inline void make_tw(float* twc, float* tws, int tid, int nthr) {
    for (int i = tid; i < 128; i += nthr) {
        float ang = (float)i * (6.283185307179586f / 256.0f);
        twc[i] = cosf(ang);
        tws[i] = sinf(ang);
    }
}

template<int T>
__device__ inline void dif_fft(float2* row, const float* twc, const float* tws,
                               float sgn, int lane) {
    #pragma unroll
    for (int s = 0; s < 8; ++s) {
        int half = 128 >> s;
        __syncthreads();
        #pragma unroll
        for (int bi = 0; bi < 128 / T; ++bi) {
            int b = lane + bi * T;
            int t = b & (half - 1);
            int blk = b >> (7 - s);
            int p0 = (blk << (8 - s)) + t;
            float2 u = row[p0];
            float2 v = row[p0 + half];
            row[p0] = make_float2(u.x + v.x, u.y + v.y);
            float dx = u.x - v.x, dy = u.y - v.y;
            int w = t << s;
            float c = twc[w], si = sgn * tws[w];
            row[p0 + half] = make_float2(dx * c - dy * si, dx * si + dy * c);
        }
    }
    __syncthreads();
}

template<int T>
__device__ inline void dit_fft(float2* row, const float* twc, const float* tws,
                               float sgn, int lane) {
    #pragma unroll
    for (int s = 0; s < 8; ++s) {
        int half = 1 << s;
        __syncthreads();
        #pragma unroll
        for (int bi = 0; bi < 128 / T; ++bi) {
            int b = lane + bi * T;
            int t = b & (half - 1);
            int blk = b >> s;
            int p0 = (blk << (s + 1)) + t;
            int w = t << (7 - s);
            float c = twc[w], si = sgn * tws[w];
            float2 v = row[p0 + half];
            float vx = v.x * c - v.y * si;
            float vy = v.x * si + v.y * c;
            float2 u = row[p0];
            row[p0] = make_float2(u.x + vx, u.y + vy);
            row[p0 + half] = make_float2(u.x - vx, u.y - vy);
        }
    }
    __syncthreads();
}

// ---------------- K0: psit[pix][f] = r^2 + i^2 (transposed, zero-padded) ----------------
__global__ void k0_psit(const float* __restrict__ r, const float* __restrict__ im,
                        float* __restrict__ psit) {
    __shared__ float tile[64 * FPAD];
    int tid = threadIdx.x;
    int base = blockIdx.x * 64;   // pixel base
    for (int idx = tid; idx < NF2 * 64; idx += 256) {
        int f = idx >> 6, px = idx & 63;
        size_t g = (size_t)f * NPIX + base + px;
        float a = r[g], b = im[g];
        tile[px * FPAD + f] = a * a + b * b;
    }
    for (int idx = tid; idx < 64 * (FPAD - NF2); idx += 256) {
        int px = idx / (FPAD - NF2), f = NF2 + idx % (FPAD - NF2);
        tile[px * FPAD + f] = 0.f;
    }
    __syncthreads();
    for (int idx = tid; idx < 64 * FPAD; idx += 256)
        psit[(size_t)base * FPAD + idx] = tile[idx];
}

// ---------------- K1: rows -> product with psi, inverse DIF over x ----------------
__global__ void k1_rowifft(const float* __restrict__ xhat,
                           const float* __restrict__ psiR,
                           const float* __restrict__ psiI,
                           float2* __restrict__ P) {
    __shared__ float2 buf[4][257];
    __shared__ float twc[128], tws[128];
    int tid = threadIdx.x;
    make_tw(twc, tws, tid, 256);
    int fi = tid >> 6, lane = tid & 63;
    int f = blockIdx.y;
    int y = blockIdx.x * 4 + fi;
    const float inv = 1.0f / 256.0f;
    size_t rb = (size_t)f * NPIX + (size_t)y * NN;
    for (int j = lane; j < NN; j += 64) {
        float xr = xhat[(y * NN + j) * 2 + 0];
        float xi = xhat[(y * NN + j) * 2 + 1];
        float pr = psiR[rb + j], pi = psiI[rb + j];
        buf[fi][j] = make_float2((xr * pr - xi * pi) * inv, (xr * pi + xi * pr) * inv);
    }
    dif_fft<64>(&buf[fi][0], twc, tws, +1.0f, lane);
    for (int j = lane; j < NN; j += 64) P[rb + j] = buf[fi][j];
}

// ---------------- K2: per column: inverse DIF over y, modulus, forward DIT over y ----------------
__global__ void k2_colpass(float2* __restrict__ P) {
    __shared__ float2 buf[16][257];
    __shared__ float twc[128], tws[128];
    int tid = threadIdx.x;      // 256 threads: 16 columns x 16 threads
    make_tw(twc, tws, tid, 256);
    int c = tid & 15, tl = tid >> 4;
    int f = blockIdx.y;
    int xb = blockIdx.x * 16;
    size_t fb = (size_t)f * NPIX;
    #pragma unroll
    for (int i = 0; i < 16; ++i) {
        int y = tl + i * 16;
        buf[c][y] = P[fb + (size_t)y * NN + xb + c];
    }
    dif_fft<16>(&buf[c][0], twc, tws, +1.0f, tl);
    const float inv = 1.0f / 256.0f;
    #pragma unroll
    for (int i = 0; i < 16; ++i) {
        int p = tl + i * 16;
        float2 v = buf[c][p];
        float vx = v.x * inv, vy = v.y * inv;
        buf[c][p] = make_float2(sqrtf(vx * vx + vy * vy + EPSF), 0.0f);
    }
    dit_fft<16>(&buf[c][0], twc, tws, -1.0f, tl);
    #pragma unroll
    for (int i = 0; i < 16; ++i) {
        int y = tl + i * 16;
        P[fb + (size_t)y * NN + xb + c] = buf[c][y];
    }
}

// ---------------- K3: rows -> forward DIT over x (consumes bitrev-x) ----------------
__global__ void k3_rowfft(float2* __restrict__ P) {
    __shared__ float2 buf[4][257];
    __shared__ float twc[128], tws[128];
    int tid = threadIdx.x;
    make_tw(twc, tws, tid, 256);
    int fi = tid >> 6, lane = tid & 63;
    int f = blockIdx.y;
    int y = blockIdx.x * 4 + fi;
    size_t rb = (size_t)f * NPIX + (size_t)y * NN;
    for (int j = lane; j < NN; j += 64) buf[fi][j] = P[rb + j];
    dit_fft<64>(&buf[fi][0], twc, tws, -1.0f, lane);
    for (int j = lane; j < NN; j += 64) P[rb + j] = buf[fi][j];
}

// ---------------- pair enumeration, SORTED by f-start group ----------------
// group g covers pairs [G[g], G[g+1]) with fstart = 8*g.
// Within group g: M pairs j=2g (36, tri a<=b), M pairs j=2g+1 (36),
//                 N pairs l=2g (8*l, skipped for g=0), N pairs l=2g+1 (8*l),
//                 then (g==4 only) A pairs (80).  s==800: s0.  801..1023: pad.
__device__ __host__ inline int fsj(int j) { int t = j >> 1; return (t > 4 ? 4 : t) * 8; }

__device__ inline int group_of(int s) {
    return (s < 80) ? 0 : (s < 192) ? 1 : (s < 336) ? 2 : (s < 512) ? 3 : 4;
}

__device__ inline void pair_sorted(int s, int& u, int& v) {
    if (s >= 800) { u = 80; v = 80; return; }   // s0 and pad
    const int Gs[5] = {0, 80, 192, 336, 512};
    int g = group_of(s);
    int r = s - Gs[g];
    if (r < 72) {                       // M section
        int j = 2 * g + (r >= 36);
        int rr = (r >= 36) ? r - 36 : r;
        int a = 0;
        while (rr >= 8 - a) { rr -= 8 - a; ++a; }
        int b = a + rr;
        u = a * 10 + j; v = b * 10 + j;
        return;
    }
    int r2 = r - 72;                    // N section
    int l0 = 2 * g;
    int c0 = (l0 >= 1) ? 8 * l0 : 0;
    if (r2 < c0) { int i = r2 / l0, j = r2 % l0; u = i * 10 + j; v = i * 10 + l0; return; }
    r2 -= c0;
    int l1 = 2 * g + 1;
    if (r2 < 8 * l1) { int i = r2 / l1, j = r2 % l1; u = i * 10 + j; v = i * 10 + l1; return; }
    r2 -= 8 * l1;                       // A section (g==4 only): r2 = i*10+j
    u = r2; v = 80;
}

// inverse maps (for c2): sorted index of each pair type
__device__ inline int pM(int a, int b, int j) {
    const int Gt[5] = {0, 80, 192, 336, 512};
    return Gt[j >> 1] + (j & 1) * 36 + a * 8 - a * (a - 1) / 2 + (b - a);
}
__device__ inline int pN(int i, int j, int l) {
    const int Gt[5] = {0, 80, 192, 336, 512};
    return Gt[l >> 1] + 72 + ((l & 1) ? 8 * (l - 1) : 0) + i * l + j;
}
// A pairs: 720 + i*10 + j ; s0: 800  (same as sorted layout)

// ---------------- C1: merged slabs, double-buffered async staging ----------------
// blockIdx.y -> (z, tile): {0:(0,0), 1:(1,0), 2:(1,1), 3:(2,0), 4:(2,1), 5:(2,2), 6:(2,3)}
// Per chunk: issue next chunk's global loads -> compute current LDS buffer ->
// vmcnt-wait + complex-mult + ds_write other buffer -> ONE barrier.
// Thread: 2 quads x 4 f x 2 pairs = 32 acc, ALL statically indexed (rule #20).
__global__ void __launch_bounds__(256) c1all(const float2* __restrict__ P,
                                             const float* __restrict__ psit,
                                             float* __restrict__ Mpart) {
    __shared__ float2 Cl[2][KC][CSTR];   // 32.9 KB: [buf][k][pair]
    __shared__ float  psl[2][KC][16];    // 1 KB
    int tid = threadIdx.x;
    int split = blockIdx.x, y = blockIdx.y;
    int z    = (y == 0) ? 0 : (y <= 2) ? 1 : 2;
    int tile = (y == 0) ? 0 : (y <= 2) ? (y - 1) : (y - 3);
    int pbase = tile * 256;

    // staging roles (hoisted once: no LUT in LDS, offsets in registers)
    int kl = tid & 7;            // k-lane 0..7
    int prow = tid >> 3;         // pair row 0..31
    int uoff[8], voff[8];
    #pragma unroll
    for (int i = 0; i < 8; ++i) {
        int u, v;
        pair_sorted(pbase + prow + 32 * i, u, v);
        uoff[i] = u * NPIX;
        voff[i] = v * NPIX;
    }
    int pk = tid >> 4, pf = tid & 15;    // psi staging (threads 0..127)
    bool do_psi = tid < 128;

    // compute roles
    int lane = tid & 63;
    int wv = tid >> 6;
    int qp = wv >> 1;            // 0..1: which quad pair of the slab
    int half = wv & 1;           // 0..1: which 128-pair half
    int p0 = half * 128 + lane;  // block-local pair

    float ar[2][4][2], ai[2][4][2];
    #pragma unroll
    for (int a = 0; a < 2; ++a)
        #pragma unroll
        for (int b = 0; b < 4; ++b)
            #pragma unroll
            for (int c = 0; c < 2; ++c) { ar[a][b][c] = 0.f; ai[a][b][c] = 0.f; }

    float2 Ast[8], Bst[8];
    float psv = 0.f;

    auto issue = [&](int ch) {
        int kb = split * KPB + ch * KC;
        #pragma unroll
        for (int i = 0; i < 8; ++i) {
            Ast[i] = P[(size_t)(uoff[i] + kb + kl)];
            Bst[i] = P[(size_t)(voff[i] + kb + kl)];
        }
        if (do_psi) psv = psit[(size_t)(kb + pk) * FPAD + z * 16 + pf];
    };
    auto write_staged = [&](int buf) {
        #pragma unroll
        for (int i = 0; i < 8; ++i) {
            Cl[buf][kl][prow + 32 * i] = make_float2(
                Ast[i].x * Bst[i].x + Ast[i].y * Bst[i].y,
                Ast[i].y * Bst[i].x - Ast[i].x * Bst[i].y);
        }
        if (do_psi) psl[buf][pk][pf] = psv;
    };

    issue(0);
    write_staged(0);
    __syncthreads();

    for (int ch = 0; ch < NCHK; ++ch) {
        int cur = ch & 1;
        if (ch + 1 < NCHK) issue(ch + 1);   // loads for next chunk in flight
        #pragma unroll
        for (int k = 0; k < KC; ++k) {
            float4 pA = *(const float4*)&psl[cur][k][qp * 8];      // quad 2qp (broadcast)
            float4 pB = *(const float4*)&psl[cur][k][qp * 8 + 4];  // quad 2qp+1
            float2 cc0 = Cl[cur][k][p0];
            float2 cc1 = Cl[cur][k][p0 + 64];
            float pq[2][4] = {{pA.x, pA.y, pA.z, pA.w}, {pB.x, pB.y, pB.z, pB.w}};
            float cr[2] = {cc0.x, cc1.x};
            float ci[2] = {cc0.y, cc1.y};
            #pragma unroll
            for (int qq = 0; qq < 2; ++qq)
                #pragma unroll
                for (int fi = 0; fi < 4; ++fi)
                    #pragma unroll
                    for (int m = 0; m < 2; ++m) {
                        ar[qq][fi][m] += pq[qq][fi] * cr[m];
                        ai[qq][fi][m] += pq[qq][fi] * ci[m];
                    }
        }
        if (ch + 1 < NCHK) write_staged(cur ^ 1);  // vmcnt wait lands here
        __syncthreads();
    }

    // private partial slot: [y*NSPL+split][fl(16)][pl(256)] float2, plain stores
    float2* out = (float2*)Mpart + (size_t)(y * NSPL + split) * 4096;
    #pragma unroll
    for (int qq = 0; qq < 2; ++qq)
        #pragma unroll
        for (int fi = 0; fi < 4; ++fi)
            #pragma unroll
            for (int m = 0; m < 2; ++m) {
                int fl = (qp * 2 + qq) * 4 + fi;   // runtime addr math, static reg idx
                out[fl * 256 + p0 + m * 64] = make_float2(ar[qq][fi][m], ai[qq][fi][m]);
            }
}

// ---------------- C1R: reduce split partials into Mout ----------------
__global__ void __launch_bounds__(256) c1red(const float* __restrict__ Mpart,
                                             float* __restrict__ Mout) {
    int y = blockIdx.x, fl = blockIdx.y;
    int pl = threadIdx.x;
    int z    = (y == 0) ? 0 : (y <= 2) ? 1 : 2;
    int tile = (y == 0) ? 0 : (y <= 2) ? (y - 1) : (y - 3);
    const float2* mp = (const float2*)Mpart;
    size_t cell = (size_t)fl * 256 + pl;
    float sx = 0.f, sy = 0.f;
    #pragma unroll 8
    for (int sp = 0; sp < NSPL; ++sp) {
        float2 v = mp[(size_t)(y * NSPL + sp) * 4096 + cell];
        sx += v.x; sy += v.y;
    }
    int f = z * 16 + fl, p = tile * 256 + pl;
    ((float2*)Mout)[(size_t)f * NPAIR_PAD + p] = make_float2(sx, sy);
}

// ---------------- C2: magnitude + assembly in reference output order ----------------
__device__ inline int seglen_d(int j, int i) {
    int s = (NF2 - fsj(j)) * (8 - i) + 9;
    for (int l = j + 1; l < 10; ++l) s += NF2 - fsj(l);
    return s;
}

__device__ inline float magof(const float* Mout, int f, int p) {
    const float nrm = 1.0f / 65536.0f;
    float re = Mout[((size_t)f * NPAIR_PAD + p) * 2 + 0] * nrm;
    float im = Mout[((size_t)f * NPAIR_PAD + p) * 2 + 1] * nrm;
    return sqrtf(re * re + im * im + EPSF);
}

__global__ void c2_assemble(const float* __restrict__ Mout, float* __restrict__ out) {
    int bid = blockIdx.x, tid = threadIdx.x;
    if (bid == 0) {
        if (tid == 0) out[0] = magof(Mout, 40, 800);   // s0
        return;
    }
    int idx = bid - 1;
    int j = idx / 8, i = idx % 8;
    int base = 1;
    for (int q = 0; q < idx; ++q) base += seglen_d(q / 8, q % 8);
    int fs = fsj(j);
    int d = 8 - i;
    int len1 = (NF2 - fs) * d;
    int total = seglen_d(j, i);
    for (int e = tid; e < total; e += 256) {
        int f, p;
        if (e < len1) {
            f = fs + e / d;
            int b = i + e % d;
            p = pM(i, b, j);
        } else {
            int e2 = e - len1;
            bool found = false;
            f = 0; p = 0;
            for (int l = j + 1; l < 10; ++l) {
                int ll = NF2 - fsj(l);
                if (e2 < ll) {
                    f = fsj(l) + e2;
                    p = pN(i, j, l);
                    found = true;
                    break;
                }
                e2 -= ll;
            }
            if (!found) { f = 32 + e2; p = 720 + i * 10 + j; }
        }
        out[base + e] = magof(Mout, f, p);
    }
}

// ---------------- launch ----------------
extern "C" void kernel_launch(void* const* d_in, const int* in_sizes, int n_in,
                              void* d_out, int out_size, void* d_ws, size_t ws_size,
                              hipStream_t stream) {
    const float* xhat  = (const float*)d_in[0];
    const float* psiR  = (const float*)d_in[1];
    const float* psiI  = (const float*)d_in[2];
    const float* p2R   = (const float*)d_in[3];
    const float* p2I   = (const float*)d_in[4];

    char* ws = (char*)d_ws;
    float2* P = (float2*)ws;
    size_t off = (size_t)NFIELD * NPIX * sizeof(float2);   // 42.47 MB
    float* psit = (float*)(ws + off);
    off += (size_t)NPIX * FPAD * sizeof(float);            // 12.58 MB
    float* Mpart = (float*)(ws + off);
    off += (size_t)7 * NSPL * 4096 * 2 * sizeof(float);    // 29.36 MB
    float* Mout = (float*)(ws + off);                      // 0.39 MB

    k0_psit<<<dim3(NPIX / 64), dim3(256), 0, stream>>>(p2R, p2I, psit);
    k1_rowifft<<<dim3(64, NFIELD), dim3(256), 0, stream>>>(xhat, psiR, psiI, P);
    k2_colpass<<<dim3(16, NFIELD), dim3(256), 0, stream>>>(P);
    k3_rowfft<<<dim3(64, NFIELD), dim3(256), 0, stream>>>(P);
    c1all<<<dim3(NSPL, 7), dim3(256), 0, stream>>>(P, psit, Mpart);
    c1red<<<dim3(7, 16), dim3(256), 0, stream>>>(Mpart, Mout);
    c2_assemble<<<dim3(81), dim3(256), 0, stream>>>(Mout, (float*)d_out);
}